// Round 7
// baseline (1254.205 us; speedup 1.0000x reference)
//
#include <hip/hip_runtime.h>

#define BB 8
#define NN 2048
#define FF 128
#define NBLK 2048
#define RPB 8       // rows per block
typedef unsigned long long ull;

// ws float layout:
//   [0,64)         barrier counters bar[0], bar[32]   (zeroed each launch)
//   [64,1088)      xsum (BB*FF)                        (zeroed each launch)
//   [1088,2112)    S (BB*FF)
//   [2112,18496)   p (BB*NN)
//   [18496,34880)  r (BB*NN)

__global__ __launch_bounds__(256, 8) void fused_gat(
    const float* __restrict__ X, const float* __restrict__ A,
    const float* __restrict__ W, const float* __restrict__ av,
    const float* __restrict__ bias_W, float* __restrict__ Hout,
    unsigned* __restrict__ bar, float* __restrict__ xsum,
    float* __restrict__ S, float* __restrict__ p, float* __restrict__ r)
{
    __shared__ float lds[NN];                   // p then r staging (8 KB)
    __shared__ float wls[FF], xls[FF], sls[FF], bwls[FF];

    const int t = threadIdx.x;
    const int lane = t & 63;
    const int wave = t >> 6;
    const int blk = blockIdx.x;
    const int row0 = blk * RPB;                 // global row base
    const int b = row0 >> 11;                   // batch

    // ---------------- phase 1: w_ai, p (8 rows), xsum atomics ----------------
    if (t < FF) {
        const float4* W4 = (const float4*)(W + t * FF);
        const float4* a4 = (const float4*)(av + FF);
        float s = 0.f;
#pragma unroll 8
        for (int f = 0; f < FF / 4; ++f) {
            const float4 w4 = W4[f], aa = a4[f];
            s += w4.x * aa.x + w4.y * aa.y + w4.z * aa.z + w4.w * aa.w;
        }
        wls[t] = s;
        xls[t] = 0.f;
    }
    __syncthreads();
    {
        const int hf = lane >> 5, l32 = lane & 31;
        const int rloc = wave * 2 + hf;                     // 8 rows/block
        const float4 wv = ((const float4*)wls)[l32];
        const float4 xv = ((const float4*)(X + (size_t)row0 * FF))[rloc * 32 + l32];
        float s = xv.x * wv.x + xv.y * wv.y + xv.z * wv.z + xv.w * wv.w;
#pragma unroll
        for (int off = 16; off; off >>= 1) s += __shfl_xor(s, off, 64);
        if (l32 == 0) p[row0 + rloc] = expf(s);
        atomicAdd(&xls[l32 * 4 + 0], xv.x);
        atomicAdd(&xls[l32 * 4 + 1], xv.y);
        atomicAdd(&xls[l32 * 4 + 2], xv.z);
        atomicAdd(&xls[l32 * 4 + 3], xv.w);
    }
    __syncthreads();
    if (t < FF) atomicAdd(&xsum[b * FF + t], xls[t]);
    __threadfence();                              // publish p + xsum adds
    __syncthreads();
    if (t == 0)
        __hip_atomic_fetch_add(&bar[0], 1u, __ATOMIC_RELEASE, __HIP_MEMORY_SCOPE_AGENT);

    // -------- phase 2: stream 2 A-rows per wave; batched loads; bits in-lane --------
    // bit (it*4+c) of bits[q] = (A[rA+q][it*256 + lane*4 + c] != 0)
    unsigned bits[2] = {0, 0};
    const int rA = row0 + wave * 2;
#pragma unroll
    for (int q = 0; q < 2; ++q) {
        const float4* Ar = (const float4*)(A + (size_t)(rA + q) * NN);
        float4 v0, v1, v2, v3, v4, v5, v6, v7;
        v0 = Ar[0 * 64 + lane]; v1 = Ar[1 * 64 + lane];
        v2 = Ar[2 * 64 + lane]; v3 = Ar[3 * 64 + lane];
        v4 = Ar[4 * 64 + lane]; v5 = Ar[5 * 64 + lane];
        v6 = Ar[6 * 64 + lane]; v7 = Ar[7 * 64 + lane];
        unsigned m = 0;
#define FOLD(v, sh) { unsigned nib = 0; \
        if ((v).x != 0.f) nib |= 1u; if ((v).y != 0.f) nib |= 2u; \
        if ((v).z != 0.f) nib |= 4u; if ((v).w != 0.f) nib |= 8u; \
        m |= nib << (sh); }
        FOLD(v0, 0) FOLD(v1, 4) FOLD(v2, 8) FOLD(v3, 12)
        FOLD(v4, 16) FOLD(v5, 20) FOLD(v6, 24) FOLD(v7, 28)
#undef FOLD
        bits[q] = m;
    }

    // barrier 0 wait (p/xsum ready device-wide; A-stream took far longer than arrivals)
    if (t == 0) {
        while (__hip_atomic_load(&bar[0], __ATOMIC_ACQUIRE, __HIP_MEMORY_SCOPE_AGENT) < NBLK)
            __builtin_amdgcn_s_sleep(1);
    }
    __syncthreads();

    // -------- phase 2b: stage p[b,:], dot bits . p, write r --------
    float4* l4 = (float4*)lds;
    {
        const float4* pg = (const float4*)(p + (size_t)b * NN);
        l4[t]       = pg[t];
        l4[t + 256] = pg[t + 256];
    }
    __syncthreads();
    {
        float acc0 = 0.f, acc1 = 0.f;
#pragma unroll
        for (int it = 0; it < 8; ++it) {
            const float4 pv = l4[it * 64 + lane];
            const unsigned n0 = (bits[0] >> (it * 4)) & 15u;
            const unsigned n1 = (bits[1] >> (it * 4)) & 15u;
            acc0 += (n0 & 1u) ? pv.x : 0.f;  acc1 += (n1 & 1u) ? pv.x : 0.f;
            acc0 += (n0 & 2u) ? pv.y : 0.f;  acc1 += (n1 & 2u) ? pv.y : 0.f;
            acc0 += (n0 & 4u) ? pv.z : 0.f;  acc1 += (n1 & 4u) ? pv.z : 0.f;
            acc0 += (n0 & 8u) ? pv.w : 0.f;  acc1 += (n1 & 8u) ? pv.w : 0.f;
        }
#pragma unroll
        for (int off = 32; off; off >>= 1) {
            acc0 += __shfl_xor(acc0, off, 64);
            acc1 += __shfl_xor(acc1, off, 64);
        }
        if (lane == 0) {
            r[rA]     = (acc0 != 0.f) ? (lds[rA & (NN - 1)] / acc0) : 0.f;
            r[rA + 1] = (acc1 != 0.f) ? (lds[(rA + 1) & (NN - 1)] / acc1) : 0.f;
        }
    }

    // designated blocks (one per batch): S = xsum . W  (xsum final after barrier 0)
    if ((blk & 255) == 0) {
        if (t < FF) {
            float s = 0.f;
#pragma unroll 8
            for (int c2 = 0; c2 < FF; ++c2) s += xsum[b * FF + c2] * W[c2 * FF + t];
            S[b * FF + t] = s;
        }
    }

    // barrier 1: publish r and S
    __threadfence();
    __syncthreads();
    if (t == 0) {
        __hip_atomic_fetch_add(&bar[32], 1u, __ATOMIC_RELEASE, __HIP_MEMORY_SCOPE_AGENT);
        while (__hip_atomic_load(&bar[32], __ATOMIC_ACQUIRE, __HIP_MEMORY_SCOPE_AGENT) < NBLK)
            __builtin_amdgcn_s_sleep(1);
    }
    __syncthreads();

    // -------- phase 3: stage r[b,:], S, bias; dot bits . r; write H --------
    {
        const float4* rg = (const float4*)(r + (size_t)b * NN);
        l4[t]       = rg[t];
        l4[t + 256] = rg[t + 256];
        if (t < FF) { sls[t] = S[(size_t)b * FF + t]; bwls[t] = bias_W[t]; }
    }
    __syncthreads();
    {
        float acc0 = 0.f, acc1 = 0.f;
#pragma unroll
        for (int it = 0; it < 8; ++it) {
            const float4 rv = l4[it * 64 + lane];
            const unsigned n0 = (bits[0] >> (it * 4)) & 15u;
            const unsigned n1 = (bits[1] >> (it * 4)) & 15u;
            acc0 += (n0 & 1u) ? rv.x : 0.f;  acc1 += (n1 & 1u) ? rv.x : 0.f;
            acc0 += (n0 & 2u) ? rv.y : 0.f;  acc1 += (n1 & 2u) ? rv.y : 0.f;
            acc0 += (n0 & 4u) ? rv.z : 0.f;  acc1 += (n1 & 4u) ? rv.z : 0.f;
            acc0 += (n0 & 8u) ? rv.w : 0.f;  acc1 += (n1 & 8u) ? rv.w : 0.f;
        }
#pragma unroll
        for (int off = 32; off; off >>= 1) {
            acc0 += __shfl_xor(acc0, off, 64);
            acc1 += __shfl_xor(acc1, off, 64);
        }
        const float2 sv = ((const float2*)sls)[lane];
        const float2 bv = ((const float2*)bwls)[lane];
        float2* H2 = (float2*)Hout;
        H2[(size_t)rA * 64 + lane] =
            make_float2(acc0 * sv.x + bv.x, acc0 * sv.y + bv.y);
        H2[(size_t)(rA + 1) * 64 + lane] =
            make_float2(acc1 * sv.x + bv.x, acc1 * sv.y + bv.y);
    }
}

extern "C" void kernel_launch(void* const* d_in, const int* in_sizes, int n_in,
                              void* d_out, int out_size, void* d_ws, size_t ws_size,
                              hipStream_t stream) {
    const float* X      = (const float*)d_in[0];
    const float* A      = (const float*)d_in[1];
    const float* W      = (const float*)d_in[2];
    const float* a      = (const float*)d_in[3];
    // d_in[4] = bias_a : algebraically cancels (rank-1 den), unused
    const float* bias_W = (const float*)d_in[5];
    float* out = (float*)d_out;

    float* ws = (float*)d_ws;
    unsigned* bar = (unsigned*)ws;        // floats [0,64)
    float* xsum  = ws + 64;               // BB*FF = 1024
    float* S     = ws + 1088;             // 1024
    float* p     = ws + 2112;             // 16384
    float* r     = ws + 18496;            // 16384

    hipMemsetAsync(ws, 0, 1088 * sizeof(float), stream);   // bar + xsum
    fused_gat<<<NBLK, 256, 0, stream>>>(X, A, W, a, bias_W, out, bar, xsum, S, p, r);
}

// Round 8
// 610.866 us; speedup vs baseline: 2.0532x; 2.0532x over previous
//
#include <hip/hip_runtime.h>

#define BB 8
#define NN 2048
#define FF 128
#define NBLK 1024
#define RPB 16      // rows per block
#define RPW 4       // rows per wave

// ws float layout:
//   [0,64)       barrier counters bar[0], bar[32]  (zeroed each launch)
//   [64,1088)    xsum (BB*FF)                      (zeroed each launch)
//   [1088,2112)  S (BB*FF)
//   [2112,18496) p (BB*NN)
//   [18496,34880) r (BB*NN)

#define GLOAD_LDS(gp, lp)                                                     \
    __builtin_amdgcn_global_load_lds(                                         \
        (const __attribute__((address_space(1))) void*)(gp),                  \
        (__attribute__((address_space(3))) void*)(lp), 16, 0, 0)

__global__ __launch_bounds__(256, 4) void fused_gat(
    const float* __restrict__ X, const float* __restrict__ A,
    const float* __restrict__ W, const float* __restrict__ av,
    const float* __restrict__ bias_W, float* __restrict__ Hout,
    unsigned* __restrict__ bar, float* __restrict__ xsum,
    float* __restrict__ S, float* __restrict__ p, float* __restrict__ r)
{
    __shared__ float lds[NN];                 // p then r staging (8 KB)
    __shared__ float aslot[4][RPW][256];      // A-stream chunks, 16 KB
    __shared__ float wls[FF], xls[FF], sls[FF], bwls[FF];

    const int t = threadIdx.x;
    const int lane = t & 63;
    const int wave = t >> 6;
    const int blk = blockIdx.x;
    const int row0 = blk * RPB;
    const int b = row0 >> 11;
    const int rA = row0 + wave * RPW;

    // ---------------- phase 1: w_ai, p (16 rows), xsum atomics ----------------
    if (t < FF) {
        const float4* W4 = (const float4*)(W + t * FF);
        const float4* a4 = (const float4*)(av + FF);
        float s = 0.f;
#pragma unroll 8
        for (int f = 0; f < FF / 4; ++f) {
            const float4 w4 = W4[f], aa = a4[f];
            s += w4.x * aa.x + w4.y * aa.y + w4.z * aa.z + w4.w * aa.w;
        }
        wls[t] = s;
        xls[t] = 0.f;
    }
    __syncthreads();
    {
        const int hf = lane >> 5, l32 = lane & 31;
        const float4 wv = ((const float4*)wls)[l32];
        const float4* X4 = (const float4*)(X + (size_t)row0 * FF);
#pragma unroll
        for (int k = 0; k < 2; ++k) {
            const int rloc = wave * 4 + k * 2 + hf;
            const float4 xv = X4[rloc * 32 + l32];
            float s = xv.x * wv.x + xv.y * wv.y + xv.z * wv.z + xv.w * wv.w;
#pragma unroll
            for (int off = 16; off; off >>= 1) s += __shfl_xor(s, off, 64);
            if (l32 == 0) p[row0 + rloc] = expf(s);
            atomicAdd(&xls[l32 * 4 + 0], xv.x);
            atomicAdd(&xls[l32 * 4 + 1], xv.y);
            atomicAdd(&xls[l32 * 4 + 2], xv.z);
            atomicAdd(&xls[l32 * 4 + 3], xv.w);
        }
    }
    __syncthreads();
    if (t < FF) atomicAdd(&xsum[b * FF + t], xls[t]);
    __threadfence();                              // publish p + xsum adds
    __syncthreads();
    if (t == 0)
        __hip_atomic_fetch_add(&bar[0], 1u, __ATOMIC_RELEASE, __HIP_MEMORY_SCOPE_AGENT);

    // -------- phase 2: stream 4 A-rows/wave via global_load_lds (1 KB/instr) --------
    // bit (c*4+j) of bq = (A[rA+q][c*256 + lane*4 + j] != 0); A is exactly 0.0/1.0
    unsigned b0 = 0, b1 = 0, b2 = 0, b3 = 0;
    {
        const float* Abase = A + (size_t)rA * NN;
        float* s0 = &aslot[wave][0][0];
        float* s1 = &aslot[wave][1][0];
        float* s2 = &aslot[wave][2][0];
        float* s3 = &aslot[wave][3][0];
#pragma unroll
        for (int c = 0; c < 8; ++c) {
            const float* g0 = Abase + c * 256 + lane * 4;
            GLOAD_LDS(g0,           s0);
            GLOAD_LDS(g0 + NN,      s1);
            GLOAD_LDS(g0 + 2 * NN,  s2);
            GLOAD_LDS(g0 + 3 * NN,  s3);
            asm volatile("s_waitcnt vmcnt(0)" ::: "memory");
            __builtin_amdgcn_sched_barrier(0);
            const uint4 v0 = ((const uint4*)s0)[lane];
            const uint4 v1 = ((const uint4*)s1)[lane];
            const uint4 v2 = ((const uint4*)s2)[lane];
            const uint4 v3 = ((const uint4*)s3)[lane];
            const int sh = c * 4;
#define NIB(v) (((v).x ? 1u : 0u) | ((v).y ? 2u : 0u) | ((v).z ? 4u : 0u) | ((v).w ? 8u : 0u))
            b0 |= NIB(v0) << sh;
            b1 |= NIB(v1) << sh;
            b2 |= NIB(v2) << sh;
            b3 |= NIB(v3) << sh;
#undef NIB
        }
    }

    // barrier 0 wait (p/xsum ready; all arrivals happened during the A-stream)
    if (t == 0) {
        while (__hip_atomic_load(&bar[0], __ATOMIC_ACQUIRE, __HIP_MEMORY_SCOPE_AGENT) < NBLK)
            __builtin_amdgcn_s_sleep(1);
    }
    __syncthreads();

    // -------- phase 2b: stage p[b,:], dot bits . p, write r --------
    float4* l4 = (float4*)lds;
    {
        const float4* pg = (const float4*)(p + (size_t)b * NN);
        l4[t]       = pg[t];
        l4[t + 256] = pg[t + 256];
    }
    __syncthreads();
    {
        float a0 = 0.f, a1 = 0.f, a2 = 0.f, a3 = 0.f;
#pragma unroll
        for (int it = 0; it < 8; ++it) {
            const float4 pv = l4[it * 64 + lane];
            const unsigned n0 = (b0 >> (it * 4)) & 15u;
            const unsigned n1 = (b1 >> (it * 4)) & 15u;
            const unsigned n2 = (b2 >> (it * 4)) & 15u;
            const unsigned n3 = (b3 >> (it * 4)) & 15u;
            a0 += (n0 & 1u) ? pv.x : 0.f;  a1 += (n1 & 1u) ? pv.x : 0.f;
            a2 += (n2 & 1u) ? pv.x : 0.f;  a3 += (n3 & 1u) ? pv.x : 0.f;
            a0 += (n0 & 2u) ? pv.y : 0.f;  a1 += (n1 & 2u) ? pv.y : 0.f;
            a2 += (n2 & 2u) ? pv.y : 0.f;  a3 += (n3 & 2u) ? pv.y : 0.f;
            a0 += (n0 & 4u) ? pv.z : 0.f;  a1 += (n1 & 4u) ? pv.z : 0.f;
            a2 += (n2 & 4u) ? pv.z : 0.f;  a3 += (n3 & 4u) ? pv.z : 0.f;
            a0 += (n0 & 8u) ? pv.w : 0.f;  a1 += (n1 & 8u) ? pv.w : 0.f;
            a2 += (n2 & 8u) ? pv.w : 0.f;  a3 += (n3 & 8u) ? pv.w : 0.f;
        }
#pragma unroll
        for (int off = 32; off; off >>= 1) {
            a0 += __shfl_xor(a0, off, 64);
            a1 += __shfl_xor(a1, off, 64);
            a2 += __shfl_xor(a2, off, 64);
            a3 += __shfl_xor(a3, off, 64);
        }
        if (lane == 0) {
            const int lr = rA & (NN - 1);
            r[rA + 0] = (a0 != 0.f) ? (lds[lr + 0] / a0) : 0.f;
            r[rA + 1] = (a1 != 0.f) ? (lds[lr + 1] / a1) : 0.f;
            r[rA + 2] = (a2 != 0.f) ? (lds[lr + 2] / a2) : 0.f;
            r[rA + 3] = (a3 != 0.f) ? (lds[lr + 3] / a3) : 0.f;
        }
    }

    // designated blocks (one per batch): S = xsum . W  (xsum final after barrier 0)
    if ((blk & 127) == 0) {
        if (t < FF) {
            float s = 0.f;
#pragma unroll 8
            for (int c2 = 0; c2 < FF; ++c2) s += xsum[b * FF + c2] * W[c2 * FF + t];
            S[b * FF + t] = s;
        }
    }

    // barrier 1: publish r and S
    __threadfence();
    __syncthreads();
    if (t == 0) {
        __hip_atomic_fetch_add(&bar[32], 1u, __ATOMIC_RELEASE, __HIP_MEMORY_SCOPE_AGENT);
        while (__hip_atomic_load(&bar[32], __ATOMIC_ACQUIRE, __HIP_MEMORY_SCOPE_AGENT) < NBLK)
            __builtin_amdgcn_s_sleep(1);
    }
    __syncthreads();

    // -------- phase 3: stage r[b,:], S, bias; dot bits . r; write H --------
    {
        const float4* rg = (const float4*)(r + (size_t)b * NN);
        l4[t]       = rg[t];
        l4[t + 256] = rg[t + 256];
        if (t < FF) { sls[t] = S[(size_t)b * FF + t]; bwls[t] = bias_W[t]; }
    }
    __syncthreads();
    {
        float a0 = 0.f, a1 = 0.f, a2 = 0.f, a3 = 0.f;
#pragma unroll
        for (int it = 0; it < 8; ++it) {
            const float4 rv = l4[it * 64 + lane];
            const unsigned n0 = (b0 >> (it * 4)) & 15u;
            const unsigned n1 = (b1 >> (it * 4)) & 15u;
            const unsigned n2 = (b2 >> (it * 4)) & 15u;
            const unsigned n3 = (b3 >> (it * 4)) & 15u;
            a0 += (n0 & 1u) ? rv.x : 0.f;  a1 += (n1 & 1u) ? rv.x : 0.f;
            a2 += (n2 & 1u) ? rv.x : 0.f;  a3 += (n3 & 1u) ? rv.x : 0.f;
            a0 += (n0 & 2u) ? rv.y : 0.f;  a1 += (n1 & 2u) ? rv.y : 0.f;
            a2 += (n2 & 2u) ? rv.y : 0.f;  a3 += (n3 & 2u) ? rv.y : 0.f;
            a0 += (n0 & 4u) ? rv.z : 0.f;  a1 += (n1 & 4u) ? rv.z : 0.f;
            a2 += (n2 & 4u) ? rv.z : 0.f;  a3 += (n3 & 4u) ? rv.z : 0.f;
            a0 += (n0 & 8u) ? rv.w : 0.f;  a1 += (n1 & 8u) ? rv.w : 0.f;
            a2 += (n2 & 8u) ? rv.w : 0.f;  a3 += (n3 & 8u) ? rv.w : 0.f;
        }
#pragma unroll
        for (int off = 32; off; off >>= 1) {
            a0 += __shfl_xor(a0, off, 64);
            a1 += __shfl_xor(a1, off, 64);
            a2 += __shfl_xor(a2, off, 64);
            a3 += __shfl_xor(a3, off, 64);
        }
        const float2 sv = ((const float2*)sls)[lane];
        const float2 bv = ((const float2*)bwls)[lane];
        float2* H2 = (float2*)Hout;
        H2[(size_t)(rA + 0) * 64 + lane] = make_float2(a0 * sv.x + bv.x, a0 * sv.y + bv.y);
        H2[(size_t)(rA + 1) * 64 + lane] = make_float2(a1 * sv.x + bv.x, a1 * sv.y + bv.y);
        H2[(size_t)(rA + 2) * 64 + lane] = make_float2(a2 * sv.x + bv.x, a2 * sv.y + bv.y);
        H2[(size_t)(rA + 3) * 64 + lane] = make_float2(a3 * sv.x + bv.x, a3 * sv.y + bv.y);
    }
}

extern "C" void kernel_launch(void* const* d_in, const int* in_sizes, int n_in,
                              void* d_out, int out_size, void* d_ws, size_t ws_size,
                              hipStream_t stream) {
    const float* X      = (const float*)d_in[0];
    const float* A      = (const float*)d_in[1];
    const float* W      = (const float*)d_in[2];
    const float* a      = (const float*)d_in[3];
    // d_in[4] = bias_a : algebraically cancels (rank-1 den), unused
    const float* bias_W = (const float*)d_in[5];
    float* out = (float*)d_out;

    float* ws = (float*)d_ws;
    unsigned* bar = (unsigned*)ws;        // floats [0,64)
    float* xsum  = ws + 64;               // BB*FF = 1024
    float* S     = ws + 1088;             // 1024
    float* p     = ws + 2112;             // 16384
    float* r     = ws + 18496;            // 16384

    hipMemsetAsync(ws, 0, 1088 * sizeof(float), stream);   // bar + xsum
    fused_gat<<<NBLK, 256, 0, stream>>>(X, A, W, a, bias_W, out, bar, xsum, S, p, r);
}

// Round 9
// 228.364 us; speedup vs baseline: 5.4921x; 2.6750x over previous
//
#include <hip/hip_runtime.h>

#define BB 8
#define NN 2048
#define FF 128

// ws float layout:
//   [0, 65536)      xpart (512 blocks x 128 col-sums of X)
//   [65536, 66560)  S (BB*FF)
//   [66560, 82944)  p (BB*NN)
//   [82944, 99328)  r (BB*NN)
//   [99328, ...)    pk: u32[B*N*64] in-lane masks (4 MB)
//                   bit (it*4+j) of pk[row*64+lane] = (A[row][it*256+lane*4+j] != 0)

// K1: p[b,n] = exp(X[b,n,:] . w_ai); xpart[blk,:] = column sums of X slice.
// grid 512 x 256; 32 rows/block; half-wave per row; w_ai recomputed per block (W is L2-hot).
__global__ __launch_bounds__(256) void k1_p_xsum(const float* __restrict__ X,
                                                 const float* __restrict__ W,
                                                 const float* __restrict__ av,
                                                 float* __restrict__ p,
                                                 float* __restrict__ xpart) {
    __shared__ float wls[FF];
    __shared__ float xls[FF];
    const int t = threadIdx.x;
    if (t < FF) {
        const float4* W4 = (const float4*)(W + t * FF);
        const float4* a4 = (const float4*)(av + FF);
        float s = 0.f;
#pragma unroll
        for (int f = 0; f < FF / 4; ++f) {
            const float4 w4 = W4[f], aa = a4[f];
            s += w4.x * aa.x + w4.y * aa.y + w4.z * aa.z + w4.w * aa.w;
        }
        wls[t] = s;
        xls[t] = 0.f;
    }
    __syncthreads();

    const int gr0 = blockIdx.x * 32;
    const int lane = t & 63, wave = t >> 6;
    const int half = lane >> 5, l32 = lane & 31;
    const float4 wv = ((const float4*)wls)[l32];
    float4 cs = make_float4(0.f, 0.f, 0.f, 0.f);
    const float4* X4 = (const float4*)(X + (size_t)gr0 * FF);

#pragma unroll
    for (int it = 0; it < 4; ++it) {
        const int rloc = wave * 8 + it * 2 + half;
        const float4 xv = X4[(size_t)rloc * 32 + l32];
        cs.x += xv.x; cs.y += xv.y; cs.z += xv.z; cs.w += xv.w;
        float s = xv.x * wv.x + xv.y * wv.y + xv.z * wv.z + xv.w * wv.w;
#pragma unroll
        for (int off = 16; off; off >>= 1) s += __shfl_xor(s, off, 64);
        if (l32 == 0) p[gr0 + rloc] = expf(s);
    }

    atomicAdd(&xls[l32 * 4 + 0], cs.x);
    atomicAdd(&xls[l32 * 4 + 1], cs.y);
    atomicAdd(&xls[l32 * 4 + 2], cs.z);
    atomicAdd(&xls[l32 * 4 + 3], cs.w);
    __syncthreads();
    if (t < FF) xpart[blockIdx.x * FF + t] = xls[t];
}

// K3: block 0: xsum = reduce(xpart); S = xsum . W.
//     blocks 1..2048: r[b,i] = p[b,i] / (A[b,i,:] . p[b,:]) (0 if denom==0)
//     + in-lane bit-pack of A into pk. 2 rows/wave; 16-load straight-line batch.
__global__ __launch_bounds__(256) void k3_r(const float* __restrict__ A,
                                            const float* __restrict__ W,
                                            const float* __restrict__ xpart,
                                            const float* __restrict__ p,
                                            float* __restrict__ r,
                                            float* __restrict__ S,
                                            unsigned* __restrict__ pk) {
    __shared__ float p_lds[NN];
    const int t = threadIdx.x;

    if (blockIdx.x == 0) {
#pragma unroll
        for (int k = 0; k < 4; ++k) {
            const int o = t + 256 * k;            // (b,f), o in [0,1024)
            const int b = o >> 7, f = o & 127;
            float s = 0.f;
            for (int j = 0; j < 64; ++j) s += xpart[(b * 64 + j) * FF + f];
            p_lds[o] = s;
        }
        __syncthreads();
#pragma unroll
        for (int k = 0; k < 4; ++k) {
            const int o = t + 256 * k;
            const int b = o >> 7, f = o & 127;
            float s = 0.f;
#pragma unroll 8
            for (int c = 0; c < FF; ++c) s += p_lds[b * FF + c] * W[c * FF + f];
            S[o] = s;
        }
        return;
    }

    const int row0 = (blockIdx.x - 1) * 8;
    const int b = row0 >> 11;
    const float4* p4 = (const float4*)(p + (size_t)b * NN);
    float4* pl4 = (float4*)p_lds;
    pl4[t]       = p4[t];
    pl4[t + 256] = p4[t + 256];
    __syncthreads();

    const int lane = t & 63, wave = t >> 6;
    const int rowA = row0 + wave * 2;
    const int rowB = rowA + 1;
    const float4* Aa = (const float4*)(A + (size_t)rowA * NN);
    const float4* Ab = (const float4*)(A + (size_t)rowB * NN);

    // straight-line 16-load batch: all A traffic in flight before any fold
    const float4 va0 = Aa[0 * 64 + lane], va1 = Aa[1 * 64 + lane];
    const float4 va2 = Aa[2 * 64 + lane], va3 = Aa[3 * 64 + lane];
    const float4 va4 = Aa[4 * 64 + lane], va5 = Aa[5 * 64 + lane];
    const float4 va6 = Aa[6 * 64 + lane], va7 = Aa[7 * 64 + lane];
    const float4 vb0 = Ab[0 * 64 + lane], vb1 = Ab[1 * 64 + lane];
    const float4 vb2 = Ab[2 * 64 + lane], vb3 = Ab[3 * 64 + lane];
    const float4 vb4 = Ab[4 * 64 + lane], vb5 = Ab[5 * 64 + lane];
    const float4 vb6 = Ab[6 * 64 + lane], vb7 = Ab[7 * 64 + lane];
    __builtin_amdgcn_sched_barrier(0);

    float accA = 0.f, accB = 0.f;
    unsigned mA = 0u, mB = 0u;
#define STEP(K, VA, VB) {                                                     \
        const float4 pv = pl4[K * 64 + lane];                                 \
        accA += VA.x * pv.x + VA.y * pv.y + VA.z * pv.z + VA.w * pv.w;        \
        accB += VB.x * pv.x + VB.y * pv.y + VB.z * pv.z + VB.w * pv.w;        \
        const unsigned na = (VA.x != 0.f ? 1u : 0u) | (VA.y != 0.f ? 2u : 0u) \
                          | (VA.z != 0.f ? 4u : 0u) | (VA.w != 0.f ? 8u : 0u);\
        const unsigned nb = (VB.x != 0.f ? 1u : 0u) | (VB.y != 0.f ? 2u : 0u) \
                          | (VB.z != 0.f ? 4u : 0u) | (VB.w != 0.f ? 8u : 0u);\
        mA |= na << (K * 4); mB |= nb << (K * 4); }
    STEP(0, va0, vb0) STEP(1, va1, vb1) STEP(2, va2, vb2) STEP(3, va3, vb3)
    STEP(4, va4, vb4) STEP(5, va5, vb5) STEP(6, va6, vb6) STEP(7, va7, vb7)
#undef STEP

    pk[(size_t)rowA * 64 + lane] = mA;
    pk[(size_t)rowB * 64 + lane] = mB;

#pragma unroll
    for (int off = 32; off; off >>= 1) {
        accA += __shfl_xor(accA, off, 64);
        accB += __shfl_xor(accB, off, 64);
    }
    if (lane == 0) {
        const int lr = rowA & (NN - 1);
        r[rowA] = (accA != 0.f) ? (p_lds[lr] / accA) : 0.f;
        r[rowB] = (accB != 0.f) ? (p_lds[lr + 1] / accB) : 0.f;
    }
}

// K4: H[b,i,f] = (A[b,i,:] . r[b,:]) * S[b,f] + bias_W[f]
// Reads in-lane masks (4 MB, cache-resident); no shuffles in the inner loop.
__global__ __launch_bounds__(256) void k4_H(const unsigned* __restrict__ pk,
                                            const float* __restrict__ rr,
                                            const float* __restrict__ S,
                                            const float* __restrict__ bias_W,
                                            float* __restrict__ Hout) {
    __shared__ float r_lds[NN];
    __shared__ float sls[FF], bwls[FF];
    const int t = threadIdx.x;
    const int row0 = blockIdx.x * 8;
    const int b = row0 >> 11;

    const float4* r4 = (const float4*)(rr + (size_t)b * NN);
    float4* rl4 = (float4*)r_lds;
    rl4[t]       = r4[t];
    rl4[t + 256] = r4[t + 256];
    if (t < FF) { sls[t] = S[b * FF + t]; bwls[t] = bias_W[t]; }
    __syncthreads();

    const int lane = t & 63, wave = t >> 6;
    const int rowA = row0 + wave * 2;
    const int rowB = rowA + 1;
    const unsigned wA = pk[(size_t)rowA * 64 + lane];
    const unsigned wB = pk[(size_t)rowB * 64 + lane];

    float accA = 0.f, accB = 0.f;
#pragma unroll
    for (int it = 0; it < 8; ++it) {
        const float4 rv = rl4[it * 64 + lane];
        const unsigned na = (wA >> (it * 4)) & 15u;
        const unsigned nb = (wB >> (it * 4)) & 15u;
        accA += (na & 1u) ? rv.x : 0.f;  accB += (nb & 1u) ? rv.x : 0.f;
        accA += (na & 2u) ? rv.y : 0.f;  accB += (nb & 2u) ? rv.y : 0.f;
        accA += (na & 4u) ? rv.z : 0.f;  accB += (nb & 4u) ? rv.z : 0.f;
        accA += (na & 8u) ? rv.w : 0.f;  accB += (nb & 8u) ? rv.w : 0.f;
    }
#pragma unroll
    for (int off = 32; off; off >>= 1) {
        accA += __shfl_xor(accA, off, 64);
        accB += __shfl_xor(accB, off, 64);
    }

    const float2 sv = ((const float2*)sls)[lane];
    const float2 bv = ((const float2*)bwls)[lane];
    float2* H2 = (float2*)Hout;
    H2[(size_t)rowA * 64 + lane] = make_float2(accA * sv.x + bv.x, accA * sv.y + bv.y);
    H2[(size_t)rowB * 64 + lane] = make_float2(accB * sv.x + bv.x, accB * sv.y + bv.y);
}

extern "C" void kernel_launch(void* const* d_in, const int* in_sizes, int n_in,
                              void* d_out, int out_size, void* d_ws, size_t ws_size,
                              hipStream_t stream) {
    const float* X      = (const float*)d_in[0];
    const float* A      = (const float*)d_in[1];
    const float* W      = (const float*)d_in[2];
    const float* a      = (const float*)d_in[3];
    // d_in[4] = bias_a : algebraically cancels (rank-1 den), unused
    const float* bias_W = (const float*)d_in[5];
    float* out = (float*)d_out;

    float* ws    = (float*)d_ws;
    float* xpart = ws;            // 65536
    float* S     = ws + 65536;    // 1024
    float* p     = ws + 66560;    // 16384
    float* r     = ws + 82944;    // 16384
    unsigned* pk = (unsigned*)(ws + 99328);  // u32[B*N*64] = 4 MB

    k1_p_xsum<<<(BB * NN) / 32, 256, 0, stream>>>(X, W, a, p, xpart);
    k3_r<<<(BB * NN) / 8 + 1, 256, 0, stream>>>(A, W, xpart, p, r, S, pk);
    k4_H<<<(BB * NN) / 8, 256, 0, stream>>>(pk, r, S, bias_W, out);
}